// Round 1
// baseline (28.503 us; speedup 1.0000x reference)
//
#include <hip/hip_runtime.h>
#include <math.h>

#define NN 2048
#define RR 10
#define MM 2048
#define CC 84
#define IOU_THR 0.5f
#define IEPS 1e-7f

// Kernel 1: one wave (64 lanes) per (n, r) pair. Scan m in chunks of 64,
// ballot on iou>thr, first set bit = first match (argmax-of-bool semantics).
__global__ __launch_bounds__(256) void match_kernel(
    const float* __restrict__ pred,
    const float* __restrict__ dpreds,
    int* __restrict__ first_idx) {
  int wid = (blockIdx.x * blockDim.x + threadIdx.x) >> 6;
  int lane = threadIdx.x & 63;
  if (wid >= NN * RR) return;
  int n = wid / RR;
  int r = wid % RR;

  // pred row stride = 84 floats = 336 B (16B-aligned) -> float4 load OK
  float4 pb = *reinterpret_cast<const float4*>(pred + (size_t)n * CC);
  float b1x1 = pb.x - pb.z * 0.5f, b1x2 = pb.x + pb.z * 0.5f;
  float b1y1 = pb.y - pb.w * 0.5f, b1y2 = pb.y + pb.w * 0.5f;
  float area1 = pb.z * pb.w;

  const float* dp = dpreds + (size_t)r * MM * 4;
  int found = -1;
  for (int m0 = 0; m0 < MM; m0 += 64) {
    int m = m0 + lane;
    float4 db = *reinterpret_cast<const float4*>(dp + (size_t)m * 4);
    float b2x1 = db.x - db.z * 0.5f, b2x2 = db.x + db.z * 0.5f;
    float b2y1 = db.y - db.w * 0.5f, b2y2 = db.y + db.w * 0.5f;
    float iw = fmaxf(fminf(b1x2, b2x2) - fmaxf(b1x1, b2x1), 0.0f);
    float ih = fmaxf(fminf(b1y2, b2y2) - fmaxf(b1y1, b2y1), 0.0f);
    float inter = iw * ih;
    float uni = area1 + db.z * db.w - inter + IEPS;
    float iou = inter / uni;
    unsigned long long bal = __ballot(iou > IOU_THR);
    if (bal) {
      found = m0 + (__ffsll((unsigned long long)bal) - 1);
      break;
    }
  }
  if (lane == 0) first_idx[wid] = found;
}

// Kernel 2: one wave per n. Lane l handles classes l and l+64 (C=84).
// entropy[c] = sum_r -p log p over matched r; softmax over c; out = 1 - min(sm).
__global__ __launch_bounds__(256) void entropy_kernel(
    const float* __restrict__ confs,
    const int* __restrict__ first_idx,
    float* __restrict__ out) {
  int lane = threadIdx.x & 63;
  int n = blockIdx.x * (blockDim.x >> 6) + (threadIdx.x >> 6);
  if (n >= NN) return;

  int idxs[RR];
  bool anym = false;
#pragma unroll
  for (int r = 0; r < RR; ++r) {
    idxs[r] = first_idx[n * RR + r];
    anym = anym || (idxs[r] >= 0);
  }

  const bool has_hi = (lane + 64) < CC;  // lanes 0..19 carry a 2nd class
  float e0 = 0.0f, e1 = 0.0f;
#pragma unroll
  for (int r = 0; r < RR; ++r) {
    if (idxs[r] >= 0) {
      const float* row = confs + ((size_t)r * MM + (size_t)idxs[r]) * CC;
      float p0 = row[lane];
      e0 -= p0 * logf(p0);
      if (has_hi) {
        float p1 = row[lane + 64];
        e1 -= p1 * logf(p1);
      }
    }
  }

  float maxE = fmaxf(e0, has_hi ? e1 : -INFINITY);
  float minE = fminf(e0, has_hi ? e1 : INFINITY);
#pragma unroll
  for (int off = 32; off >= 1; off >>= 1) {
    maxE = fmaxf(maxE, __shfl_xor(maxE, off));
    minE = fminf(minE, __shfl_xor(minE, off));
  }
  float s = expf(e0 - maxE) + (has_hi ? expf(e1 - maxE) : 0.0f);
#pragma unroll
  for (int off = 32; off >= 1; off >>= 1) s += __shfl_xor(s, off);

  float result = anym ? (1.0f - expf(minE - maxE) / s) : nanf("");
  if (lane == 0) out[n] = result;
}

extern "C" void kernel_launch(void* const* d_in, const int* in_sizes, int n_in,
                              void* d_out, int out_size, void* d_ws, size_t ws_size,
                              hipStream_t stream) {
  const float* pred   = (const float*)d_in[0];   // (N, 84)
  const float* dpreds = (const float*)d_in[1];   // (R, M, 4)
  const float* confs  = (const float*)d_in[2];   // (R, M, 84)
  float* out = (float*)d_out;                    // (N,)
  int* first_idx = (int*)d_ws;                   // N*R ints

  // Kernel 1: N*R waves, 4 waves/block
  {
    int total_waves = NN * RR;                   // 20480
    int blocks = (total_waves * 64 + 255) / 256; // 5120
    match_kernel<<<blocks, 256, 0, stream>>>(pred, dpreds, first_idx);
  }
  // Kernel 2: one wave per n, 4 waves/block
  {
    int blocks = (NN + 3) / 4;                   // 512
    entropy_kernel<<<blocks, 256, 0, stream>>>(confs, first_idx, out);
  }
}

// Round 2
// 23.091 us; speedup vs baseline: 1.2344x; 1.2344x over previous
//
#include <hip/hip_runtime.h>
#include <math.h>

#define NN 2048
#define RR 10
#define MM 2048
#define CC 84
#define IEPS 1e-7f

// Kernel 1: one wave (64 lanes) per (n, r) pair. Scan m in chunks of 256
// (4 x 64 independent loads in flight), ballot on hit, first set bit in
// m-order = first match (argmax-of-bool semantics). Division-free compare:
// inter/(a1+a2-inter+eps) > 0.5  <=>  3*inter > a1+a2+eps.
__global__ __launch_bounds__(256) void match_kernel(
    const float* __restrict__ pred,
    const float* __restrict__ dpreds,
    int* __restrict__ first_idx) {
  int wid = (blockIdx.x * blockDim.x + threadIdx.x) >> 6;
  int lane = threadIdx.x & 63;
  if (wid >= NN * RR) return;
  int n = wid / RR;
  int r = wid - n * RR;

  // pred row stride = 84 floats = 336 B (16B-aligned) -> float4 load OK
  float4 pb = *reinterpret_cast<const float4*>(pred + (size_t)n * CC);
  const float b1x1 = fmaf(-0.5f, pb.z, pb.x), b1x2 = fmaf(0.5f, pb.z, pb.x);
  const float b1y1 = fmaf(-0.5f, pb.w, pb.y), b1y2 = fmaf(0.5f, pb.w, pb.y);
  const float a1e = pb.z * pb.w + IEPS;  // area1 + eps

  const float4* __restrict__ dp =
      reinterpret_cast<const float4*>(dpreds + (size_t)r * MM * 4);

  int found = -1;
  for (int m0 = 0; m0 < MM; m0 += 256) {
    // 4 independent 16B loads in flight
    float4 d0 = dp[m0 + lane];
    float4 d1 = dp[m0 + 64 + lane];
    float4 d2 = dp[m0 + 128 + lane];
    float4 d3 = dp[m0 + 192 + lane];

#define HIT(db, h)                                                          \
    {                                                                       \
      float x1 = fmaf(-0.5f, db.z, db.x), x2 = fmaf(0.5f, db.z, db.x);      \
      float y1 = fmaf(-0.5f, db.w, db.y), y2 = fmaf(0.5f, db.w, db.y);      \
      float iw = fmaxf(fminf(b1x2, x2) - fmaxf(b1x1, x1), 0.0f);            \
      float ih = fmaxf(fminf(b1y2, y2) - fmaxf(b1y1, y1), 0.0f);            \
      float inter = iw * ih;                                                \
      float t = db.z * db.w + a1e; /* a2 + a1 + eps */                      \
      h = (3.0f * inter > t);                                               \
    }
    bool h0, h1, h2, h3;
    HIT(d0, h0) HIT(d1, h1) HIT(d2, h2) HIT(d3, h3)
#undef HIT

    unsigned long long b0 = __ballot(h0);
    unsigned long long b1 = __ballot(h1);
    unsigned long long b2 = __ballot(h2);
    unsigned long long b3 = __ballot(h3);
    if (b0 | b1 | b2 | b3) {
      if (b0)      found = m0 +       (__ffsll(b0) - 1);
      else if (b1) found = m0 + 64  + (__ffsll(b1) - 1);
      else if (b2) found = m0 + 128 + (__ffsll(b2) - 1);
      else         found = m0 + 192 + (__ffsll(b3) - 1);
      break;
    }
  }
  if (lane == 0) first_idx[wid] = found;
}

// Kernel 2: one wave per n. Lane l handles classes l and l+64 (C=84).
// entropy[c] = sum_r -p log p over matched r; softmax over c; out = 1 - min(sm).
__global__ __launch_bounds__(256) void entropy_kernel(
    const float* __restrict__ confs,
    const int* __restrict__ first_idx,
    float* __restrict__ out) {
  int lane = threadIdx.x & 63;
  int n = blockIdx.x * (blockDim.x >> 6) + (threadIdx.x >> 6);
  if (n >= NN) return;

  int idxs[RR];
  bool anym = false;
#pragma unroll
  for (int r = 0; r < RR; ++r) {
    idxs[r] = first_idx[n * RR + r];
    anym = anym || (idxs[r] >= 0);
  }

  const bool has_hi = (lane + 64) < CC;  // lanes 0..19 carry a 2nd class
  float e0 = 0.0f, e1 = 0.0f;
#pragma unroll
  for (int r = 0; r < RR; ++r) {
    if (idxs[r] >= 0) {
      const float* row = confs + ((size_t)r * MM + (size_t)idxs[r]) * CC;
      float p0 = row[lane];
      e0 -= p0 * __logf(p0);
      if (has_hi) {
        float p1 = row[lane + 64];
        e1 -= p1 * __logf(p1);
      }
    }
  }

  float maxE = fmaxf(e0, has_hi ? e1 : -INFINITY);
  float minE = fminf(e0, has_hi ? e1 : INFINITY);
#pragma unroll
  for (int off = 32; off >= 1; off >>= 1) {
    maxE = fmaxf(maxE, __shfl_xor(maxE, off));
    minE = fminf(minE, __shfl_xor(minE, off));
  }
  float s = __expf(e0 - maxE) + (has_hi ? __expf(e1 - maxE) : 0.0f);
#pragma unroll
  for (int off = 32; off >= 1; off >>= 1) s += __shfl_xor(s, off);

  float result = anym ? (1.0f - __expf(minE - maxE) / s) : nanf("");
  if (lane == 0) out[n] = result;
}

extern "C" void kernel_launch(void* const* d_in, const int* in_sizes, int n_in,
                              void* d_out, int out_size, void* d_ws, size_t ws_size,
                              hipStream_t stream) {
  const float* pred   = (const float*)d_in[0];   // (N, 84)
  const float* dpreds = (const float*)d_in[1];   // (R, M, 4)
  const float* confs  = (const float*)d_in[2];   // (R, M, 84)
  float* out = (float*)d_out;                    // (N,)
  int* first_idx = (int*)d_ws;                   // N*R ints

  // Kernel 1: N*R waves, 4 waves/block
  {
    int total_waves = NN * RR;                   // 20480
    int blocks = (total_waves * 64 + 255) / 256; // 5120
    match_kernel<<<blocks, 256, 0, stream>>>(pred, dpreds, first_idx);
  }
  // Kernel 2: one wave per n, 4 waves/block
  {
    int blocks = (NN + 3) / 4;                   // 512
    entropy_kernel<<<blocks, 256, 0, stream>>>(confs, first_idx, out);
  }
}